// Round 1
// baseline (17.613 us; speedup 1.0000x reference)
//
#include <hip/hip_runtime.h>

#define B_ 2048
#define S_ 512
#define V_ 32128
#define H_ 16
#define O_ 16

// ---------------------------------------------------------------------------
// Transpose enc1_w [H=16, V] -> wT [V, 16] so a per-token gather is one
// contiguous 64B read. LDS-tiled: coalesced reads AND coalesced writes.
// V = 32128 = 251 * 128, so grid of 251 blocks, 128-column tiles, no bounds.
// ---------------------------------------------------------------------------
__global__ __launch_bounds__(256) void transpose_w_kernel(
    const float* __restrict__ w,   // [16, V]
    float* __restrict__ wT)        // [V, 16]
{
    __shared__ float tile[16][129];   // +1 pad: bank = (129*h+v)%32 = (h+v)%32
    const int t  = threadIdx.x;
    const int v0 = blockIdx.x * 128;

#pragma unroll
    for (int i = 0; i < 8; ++i) {          // 16 rows x 128 cols = 2048 elems
        int idx = i * 256 + t;
        int h   = idx >> 7;                // 0..15
        int vl  = idx & 127;
        tile[h][vl] = w[(size_t)h * V_ + v0 + vl];   // coalesced per row
    }
    __syncthreads();
#pragma unroll
    for (int i = 0; i < 8; ++i) {
        int idx = i * 256 + t;
        int vl  = idx >> 4;                // 0..127
        int h   = idx & 15;
        wT[(size_t)(v0 + vl) * 16 + h] = tile[h][vl]; // coalesced write
    }
}

// ---------------------------------------------------------------------------
// One block per batch row. h_pre[h] = sum_s enc1_w[h, x[b,s]]  (histogram
// matmul == gather-accumulate). Then relu + two 16x16 matvecs.
// TR=true: table is wT [V,16] (contiguous float4 gathers).
// TR=false: table is enc1_w [16,V] (fallback if workspace too small).
// ---------------------------------------------------------------------------
template <bool TR>
__global__ __launch_bounds__(256) void encoder_kernel(
    const int*   __restrict__ x,        // [B, S]
    const float* __restrict__ table,
    const float* __restrict__ enc1_b,   // [16]
    const float* __restrict__ mean_w,   // [16,16]
    const float* __restrict__ mean_b,   // [16]
    const float* __restrict__ logvar_w, // [16,16]
    const float* __restrict__ logvar_b, // [16]
    float*       __restrict__ out)      // mean [B,16] then logvar [B,16]
{
    __shared__ int   toks[S_];
    __shared__ float hred[4][16];
    __shared__ float hvec[16];

    const int t = threadIdx.x;
    const int b = blockIdx.x;

    // Stage the row's 512 token ids (coalesced 8B per thread).
    {
        const int2* xr = (const int2*)(x + (size_t)b * S_);
        ((int2*)toks)[t] = xr[t];
    }
    __syncthreads();

    // 64 groups of 4 threads; thread owns h-quad q (4 of the 16 h's).
    const int q = t & 3;
    const int g = t >> 2;     // 0..63
    float a0 = 0.f, a1 = 0.f, a2 = 0.f, a3 = 0.f;

#pragma unroll
    for (int j = 0; j < 8; ++j) {
        int v = toks[j * 64 + g];          // conflict-free LDS (16 consec addrs/wave)
        if (TR) {
            float4 w4 = ((const float4*)table)[(size_t)v * 4 + q];
            a0 += w4.x; a1 += w4.y; a2 += w4.z; a3 += w4.w;
        } else {
            a0 += table[(size_t)(q * 4 + 0) * V_ + v];
            a1 += table[(size_t)(q * 4 + 1) * V_ + v];
            a2 += table[(size_t)(q * 4 + 2) * V_ + v];
            a3 += table[(size_t)(q * 4 + 3) * V_ + v];
        }
    }

    // Reduce across the 16 groups within each wave (q position preserved).
#pragma unroll
    for (int m = 4; m <= 32; m <<= 1) {
        a0 += __shfl_xor(a0, m);
        a1 += __shfl_xor(a1, m);
        a2 += __shfl_xor(a2, m);
        a3 += __shfl_xor(a3, m);
    }

    const int wave = t >> 6;
    const int lane = t & 63;
    if (lane < 4) {                 // lane == q for lanes 0..3
        hred[wave][lane * 4 + 0] = a0;
        hred[wave][lane * 4 + 1] = a1;
        hred[wave][lane * 4 + 2] = a2;
        hred[wave][lane * 4 + 3] = a3;
    }
    __syncthreads();

    if (t < 16) {
        float s = hred[0][t] + hred[1][t] + hred[2][t] + hred[3][t] + enc1_b[t];
        hvec[t] = fmaxf(s, 0.0f);
    }
    __syncthreads();

    // Two 16x16 matvecs: threads 0..15 -> mean, threads 16..31 -> logvar.
    if (t < 32) {
        const int    o  = t & 15;
        const float* W  = (t < 16) ? mean_w : logvar_w;
        const float* Bv = (t < 16) ? mean_b : logvar_b;
        float s = Bv[o];
#pragma unroll
        for (int k = 0; k < 16; ++k) s += W[o * 16 + k] * hvec[k];
        const size_t off = (t < 16) ? 0 : (size_t)B_ * O_;
        out[off + (size_t)b * O_ + o] = s;
    }
}

extern "C" void kernel_launch(void* const* d_in, const int* in_sizes, int n_in,
                              void* d_out, int out_size, void* d_ws, size_t ws_size,
                              hipStream_t stream) {
    const int*   x        = (const int*)d_in[0];
    const float* enc1_w   = (const float*)d_in[1];
    const float* enc1_b   = (const float*)d_in[2];
    const float* mean_w   = (const float*)d_in[3];
    const float* mean_b   = (const float*)d_in[4];
    const float* logvar_w = (const float*)d_in[5];
    const float* logvar_b = (const float*)d_in[6];
    float*       out      = (float*)d_out;

    const size_t wT_bytes = (size_t)V_ * H_ * sizeof(float);
    if (ws_size >= wT_bytes) {
        float* wT = (float*)d_ws;
        transpose_w_kernel<<<V_ / 128, 256, 0, stream>>>(enc1_w, wT);
        encoder_kernel<true><<<B_, 256, 0, stream>>>(
            x, wT, enc1_b, mean_w, mean_b, logvar_w, logvar_b, out);
    } else {
        encoder_kernel<false><<<B_, 256, 0, stream>>>(
            x, enc1_w, enc1_b, mean_w, mean_b, logvar_w, logvar_b, out);
    }
}